// Round 10
// baseline (156.165 us; speedup 1.0000x reference)
//
#include <hip/hip_runtime.h>
#include <hip/hip_fp16.h>

#define D     2048
#define BLK   256
#define EPSV  1e-5f

typedef _Float16 h2 __attribute__((ext_vector_type(2)));

__device__ __forceinline__ unsigned int pkh(float a, float b) {
    return __builtin_bit_cast(unsigned int, __builtin_amdgcn_cvt_pkrtz(a, b));
}
__device__ __forceinline__ h2 ash2(unsigned int u) {
    return __builtin_bit_cast(h2, u);
}

// DPP row_shr:N add (old=0 -> lanes with no source contribute 0)
template<int CTRL>
__device__ __forceinline__ float dppadd(float x) {
    int y = __builtin_amdgcn_update_dpp(0, __builtin_bit_cast(int, x), CTRL, 0xf, 0xf, false);
    return x + __builtin_bit_cast(float, y);
}
// full wave64 sum; result valid in lanes 15,31,47,63
__device__ __forceinline__ float wave_sum(float x) {
    x += __shfl_xor(x, 32, 64);
    x += __shfl_xor(x, 16, 64);
    x = dppadd<0x111>(x);   // row_shr:1
    x = dppadd<0x112>(x);   // row_shr:2
    x = dppadd<0x114>(x);   // row_shr:4
    x = dppadd<0x118>(x);   // row_shr:8
    return x;
}

// ---- weight prep: Wq[c][p] = packed f16 pair of column c at d={2p,2p+1}; S[c] = sum_d w[c][d]
// c: 0-3 Wb, 4-7 Wm, 8-23 Wr(i*4+j). Grid: 24 blocks x 256 threads.
__global__ __launch_bounds__(256) void wt_kernel(
    const float* __restrict__ Wb, const float* __restrict__ Wm,
    const float* __restrict__ Wr, unsigned int* __restrict__ Wq,
    float* __restrict__ S)
{
    const int c = blockIdx.x;
    const int t = threadIdx.x;
    const float* src;
    int stride;
    if (c < 4)       { src = Wb + c;       stride = 4;  }
    else if (c < 8)  { src = Wm + (c - 4); stride = 4;  }
    else             { src = Wr + (c - 8); stride = 16; }

    float s = 0.f;
    #pragma unroll
    for (int k = 0; k < 4; ++k) {
        int p = t + 256 * k;                    // pair index 0..1023
        float a = src[(2 * p)     * stride];
        float b = src[(2 * p + 1) * stride];
        s += a + b;
        Wq[c * 1024 + p] = pkh(a, b);
    }
    __shared__ float rsum[4];
    #pragma unroll
    for (int off = 32; off; off >>= 1) s += __shfl_xor(s, off, 64);
    if ((t & 63) == 0) rsum[t >> 6] = s;
    __syncthreads();
    if (t == 0) S[c] = rsum[0] + rsum[1] + rsum[2] + rsum[3];
}

__global__ __launch_bounds__(BLK) void hc_kernel(
    const float* __restrict__ lo,      // [tok, D]
    const float* __restrict__ hs,      // [tok, 4, D]
    const float* __restrict__ Bm,      // [1,4]
    const float* __restrict__ Am,      // [4,1]
    const float* __restrict__ Ar,      // [4,4]
    const float* __restrict__ s_alpha, // [4,4]
    const float* __restrict__ s_beta,  // [1,4]
    const unsigned int* __restrict__ Wq, // [24][1024] packed f16 weight pairs
    const float* __restrict__ S,       // [24] column sums
    float* __restrict__ out)           // [tok, 4, D]
{
    __shared__ __align__(16) unsigned int hq[4][1024];   // 16 KB f16-packed hidden rows
    __shared__ float Rl[24][4];
    __shared__ float sred[4][2];
    __shared__ float coefs[24];

    const int tid  = threadIdx.x;
    const int wave = tid >> 6;             // wave w owns hidden row w
    const int lane = tid & 63;
    const long tok = blockIdx.x;

    const float4* hs4  = (const float4*)(hs + tok * (long)(4 * D));
    const float4* lo4  = (const float4*)(lo + tok * (long)D);
    float4*       out4 = (float4*)(out + tok * (long)(4 * D));

    // ---- Phase 1: wave loads its full row (lane-contiguous float4), stats + f16 pack ----
    float4 hv[8];
    const int rbase = wave * 512 + lane;
    #pragma unroll
    for (int k = 0; k < 8; ++k) hv[k] = hs4[rbase + 64 * k];
    float4 lv0 = lo4[tid];                 // lo prefetched for phase 3
    float4 lv1 = lo4[tid + 256];

    float s = 0.f, q = 0.f;
    uint2* hqw = (uint2*)hq[wave];
    #pragma unroll
    for (int k = 0; k < 8; ++k) {
        float4 v = hv[k];
        s += v.x + v.y + v.z + v.w;
        q += v.x * v.x + v.y * v.y + v.z * v.z + v.w * v.w;
        uint2 p;
        p.x = pkh(v.x, v.y);
        p.y = pkh(v.z, v.w);
        hqw[lane + 64 * k] = p;
    }
    s = wave_sum(s);
    q = wave_sum(q);
    if (lane == 15) { sred[wave][0] = s; sred[wave][1] = q; }
    __syncthreads();                       // bar1: hq + sred ready

    // ---- Phase 2: wave owns cols 6w..6w+5, all 4 rows ----
    float acc[6][4];
    #pragma unroll
    for (int j = 0; j < 6; ++j)
        #pragma unroll
        for (int n = 0; n < 4; ++n) acc[j][n] = 0.f;

    const int c0 = wave * 6;
    const uint2* Wq2 = (const uint2*)Wq;   // [24][512]

    #pragma unroll
    for (int k = 0; k < 8; ++k) {
        int i = 64 * k + lane;             // lane-contiguous
        uint2 hr[4];
        #pragma unroll
        for (int n = 0; n < 4; ++n) hr[n] = ((const uint2*)hq[n])[i];
        #pragma unroll
        for (int j = 0; j < 6; ++j) {
            uint2 w = Wq2[(c0 + j) * 512 + i];
            #pragma unroll
            for (int n = 0; n < 4; ++n) {
                acc[j][n] = __builtin_amdgcn_fdot2(ash2(hr[n].x), ash2(w.x), acc[j][n], false);
                acc[j][n] = __builtin_amdgcn_fdot2(ash2(hr[n].y), ash2(w.y), acc[j][n], false);
            }
        }
    }
    #pragma unroll
    for (int j = 0; j < 6; ++j)
        #pragma unroll
        for (int n = 0; n < 4; ++n) {
            float v = wave_sum(acc[j][n]);
            if (lane == 15) Rl[c0 + j][n] = v;
        }
    __syncthreads();                       // bar2: Rl ready

    // ---- Combine: coef[c] = affine(tanh(0.25 * sum_n rs[n]*(R[n][c] - mu[n]*S[c]))) ----
    if (tid < 24) {
        int c = tid;
        float Sc = S[c];
        float raw = 0.f;
        #pragma unroll
        for (int n = 0; n < 4; ++n) {
            float ss = sred[n][0];
            float qq = sred[n][1];
            float m   = ss * (1.f / D);
            float var = qq * (1.f / D) - m * m;
            float r   = rsqrtf(var + EPSV);
            raw += r * (Rl[c][n] - m * Sc);
        }
        raw *= 0.25f;
        float t = tanhf(raw);
        float cv;
        if (c < 4) {
            cv = s_beta[c] * t + Bm[c];
        } else if (c < 8) {
            int n = c - 4;
            cv = s_alpha[n * 4] * t + Am[n];
        } else {
            int ij = c - 8;
            cv = s_alpha[ij] * t + Ar[ij];
        }
        coefs[c] = cv;
    }
    __syncthreads();                       // bar3: coefs ready

    float Bd[4], Amd[4], Ard[4][4];
    #pragma unroll
    for (int n = 0; n < 4; ++n) { Bd[n] = coefs[n]; Amd[n] = coefs[4 + n]; }
    #pragma unroll
    for (int i = 0; i < 4; ++i)
        #pragma unroll
        for (int j = 0; j < 4; ++j) Ard[i][j] = coefs[8 + i * 4 + j];

    // ---- Phase 3: outputs; thread owns float4 slots {tid, tid+256} ----
    #pragma unroll
    for (int k = 0; k < 2; ++k) {
        int d4 = tid + 256 * k;
        float4 h[4];
        #pragma unroll
        for (int n = 0; n < 4; ++n) {
            uint2 r = ((const uint2*)hq[n])[d4];
            h2 a = ash2(r.x), b = ash2(r.y);
            h[n].x = (float)a[0]; h[n].y = (float)a[1];
            h[n].z = (float)b[0]; h[n].w = (float)b[1];
        }
        float4 lv = (k == 0) ? lv0 : lv1;
        float4 mx = {0.f, 0.f, 0.f, 0.f};
        #pragma unroll
        for (int n = 0; n < 4; ++n) {
            mx.x += Amd[n] * h[n].x; mx.y += Amd[n] * h[n].y;
            mx.z += Amd[n] * h[n].z; mx.w += Amd[n] * h[n].w;
        }
        #pragma unroll
        for (int i = 0; i < 4; ++i) {
            float4 o;
            o.x = Bd[i] * lv.x + mx.x;
            o.y = Bd[i] * lv.y + mx.y;
            o.z = Bd[i] * lv.z + mx.z;
            o.w = Bd[i] * lv.w + mx.w;
            #pragma unroll
            for (int j = 0; j < 4; ++j) {
                o.x += Ard[i][j] * h[j].x;
                o.y += Ard[i][j] * h[j].y;
                o.z += Ard[i][j] * h[j].z;
                o.w += Ard[i][j] * h[j].w;
            }
            out4[i * 512 + d4] = o;
        }
    }
}

extern "C" void kernel_launch(void* const* d_in, const int* in_sizes, int n_in,
                              void* d_out, int out_size, void* d_ws, size_t ws_size,
                              hipStream_t stream) {
    const float* lo      = (const float*)d_in[0];
    const float* hs      = (const float*)d_in[1];
    const float* Bm      = (const float*)d_in[2];
    const float* Am      = (const float*)d_in[3];
    const float* Ar      = (const float*)d_in[4];
    const float* s_alpha = (const float*)d_in[5];
    const float* s_beta  = (const float*)d_in[6];
    const float* Wb      = (const float*)d_in[7];
    const float* Wm      = (const float*)d_in[8];
    const float* Wr      = (const float*)d_in[9];
    float* out = (float*)d_out;

    unsigned int* Wq = (unsigned int*)d_ws;                    // 98304 B
    float* S         = (float*)((char*)d_ws + 24 * 1024 * 4);  // 96 B

    wt_kernel<<<24, 256, 0, stream>>>(Wb, Wm, Wr, Wq, S);

    const int tokens = in_sizes[0] / D;            // 8192
    hc_kernel<<<tokens, BLK, 0, stream>>>(lo, hs, Bm, Am, Ar, s_alpha, s_beta,
                                          Wq, S, out);
}

// Round 11
// 143.335 us; speedup vs baseline: 1.0895x; 1.0895x over previous
//
#include <hip/hip_runtime.h>
#include <hip/hip_fp16.h>

#define D     2048
#define BLK   512
#define EPSV  1e-5f

typedef _Float16 h2 __attribute__((ext_vector_type(2)));

__device__ __forceinline__ unsigned int pkh(float a, float b) {
    return __builtin_bit_cast(unsigned int, __builtin_amdgcn_cvt_pkrtz(a, b));
}
__device__ __forceinline__ h2 ash2(unsigned int u) {
    return __builtin_bit_cast(h2, u);
}

// DPP row_shr:N add (old=0 -> lanes with no source contribute 0)
template<int CTRL>
__device__ __forceinline__ float dppadd(float x) {
    int y = __builtin_amdgcn_update_dpp(0, __builtin_bit_cast(int, x), CTRL, 0xf, 0xf, false);
    return x + __builtin_bit_cast(float, y);
}
// full wave64 sum; result valid in lanes 15,31,47,63
__device__ __forceinline__ float wave_sum(float x) {
    x += __shfl_xor(x, 32, 64);
    x += __shfl_xor(x, 16, 64);
    x = dppadd<0x111>(x);   // row_shr:1
    x = dppadd<0x112>(x);   // row_shr:2
    x = dppadd<0x114>(x);   // row_shr:4
    x = dppadd<0x118>(x);   // row_shr:8
    return x;
}

__device__ __forceinline__ float rdlane(float v, int l) {
    return __builtin_bit_cast(float, __builtin_amdgcn_readlane(__builtin_bit_cast(int, v), l));
}

// ---- weight prep: Wq[c][p] = packed f16 pair of column c at d={2p,2p+1}; S[c] = sum_d w[c][d]
// c: 0-3 Wb, 4-7 Wm, 8-23 Wr(i*4+j). Grid: 24 blocks x 256 threads.
__global__ __launch_bounds__(256) void wt_kernel(
    const float* __restrict__ Wb, const float* __restrict__ Wm,
    const float* __restrict__ Wr, unsigned int* __restrict__ Wq,
    float* __restrict__ S)
{
    const int c = blockIdx.x;
    const int t = threadIdx.x;
    const float* src;
    int stride;
    if (c < 4)       { src = Wb + c;       stride = 4;  }
    else if (c < 8)  { src = Wm + (c - 4); stride = 4;  }
    else             { src = Wr + (c - 8); stride = 16; }

    float s = 0.f;
    #pragma unroll
    for (int k = 0; k < 4; ++k) {
        int p = t + 256 * k;                    // pair index 0..1023
        float a = src[(2 * p)     * stride];
        float b = src[(2 * p + 1) * stride];
        s += a + b;
        Wq[c * 1024 + p] = pkh(a, b);
    }
    __shared__ float rsum[4];
    #pragma unroll
    for (int off = 32; off; off >>= 1) s += __shfl_xor(s, off, 64);
    if ((t & 63) == 0) rsum[t >> 6] = s;
    __syncthreads();
    if (t == 0) S[c] = rsum[0] + rsum[1] + rsum[2] + rsum[3];
}

__global__ __launch_bounds__(BLK) void hc_kernel(
    const float* __restrict__ lo,      // [tok, D]
    const float* __restrict__ hs,      // [tok, 4, D]
    const float* __restrict__ Bm,      // [1,4]
    const float* __restrict__ Am,      // [4,1]
    const float* __restrict__ Ar,      // [4,4]
    const float* __restrict__ s_alpha, // [4,4]
    const float* __restrict__ s_beta,  // [1,4]
    const unsigned int* __restrict__ Wq, // [24][1024] packed f16 weight pairs
    const float* __restrict__ S,       // [24] column sums
    float* __restrict__ out)           // [tok, 4, D]
{
    __shared__ __align__(16) unsigned int hq[4][1024];   // 16 KB: f16-packed hidden rows
    __shared__ float Rl[24][4];            // raw dots R[c][n]
    __shared__ float sred[8][2];           // per-wave row-half {sum, sumsq}

    const int tid  = threadIdx.x;
    const int wave = tid >> 6;
    const int lane = tid & 63;
    const int row  = wave >> 1;            // P1: wave pair per hidden row
    const int half = wave & 1;
    const long tok = blockIdx.x;

    const float4* hs4  = (const float4*)(hs + tok * (long)(4 * D));
    const float4* lo4  = (const float4*)(lo + tok * (long)D);
    float4*       out4 = (float4*)(out + tok * (long)(4 * D));

    // ---- Phase 1: wave loads its half-row (lane-contiguous float4), stats + f16 pack ----
    float4 hv[4];
    const int base = row * 512 + half * 256 + lane;
    #pragma unroll
    for (int k = 0; k < 4; ++k) hv[k] = hs4[base + 64 * k];
    float4 lv = lo4[tid];                  // 512 threads cover the lo row; used in phase 3

    float s = 0.f, q = 0.f;
    uint2* hq2w = (uint2*)hq[row];
    #pragma unroll
    for (int k = 0; k < 4; ++k) {
        float4 v = hv[k];
        s += v.x + v.y + v.z + v.w;
        q += v.x * v.x + v.y * v.y + v.z * v.z + v.w * v.w;
        uint2 p;
        p.x = pkh(v.x, v.y);
        p.y = pkh(v.z, v.w);
        hq2w[half * 256 + 64 * k + lane] = p;
    }
    s = wave_sum(s);
    q = wave_sum(q);
    if (lane == 15) { sred[wave][0] = s; sred[wave][1] = q; }
    __syncthreads();                       // bar1: hq + sred ready

    // ---- Phase 2: raw dots R[n][c]; wave owns cols 3w..3w+2, all 4 rows ----
    float acc[3][4];
    #pragma unroll
    for (int j = 0; j < 3; ++j)
        #pragma unroll
        for (int n = 0; n < 4; ++n) acc[j][n] = 0.f;

    const int c0 = wave * 3;
    const uint2* Wq2 = (const uint2*)Wq;   // [24][512] uint2

    #pragma unroll
    for (int k = 0; k < 8; ++k) {
        int i = 64 * k + lane;             // uint2 index, lane-contiguous
        uint2 hr[4];
        #pragma unroll
        for (int n = 0; n < 4; ++n) hr[n] = ((const uint2*)hq[n])[i];
        uint2 wv[3];
        #pragma unroll
        for (int j = 0; j < 3; ++j) wv[j] = Wq2[(c0 + j) * 512 + i];
        #pragma unroll
        for (int j = 0; j < 3; ++j)
            #pragma unroll
            for (int n = 0; n < 4; ++n) {
                acc[j][n] = __builtin_amdgcn_fdot2(ash2(hr[n].x), ash2(wv[j].x), acc[j][n], false);
                acc[j][n] = __builtin_amdgcn_fdot2(ash2(hr[n].y), ash2(wv[j].y), acc[j][n], false);
            }
    }
    #pragma unroll
    for (int j = 0; j < 3; ++j)
        #pragma unroll
        for (int n = 0; n < 4; ++n) {
            float v = wave_sum(acc[j][n]);
            if (lane == 15) Rl[c0 + j][n] = v;
        }
    __syncthreads();                       // bar2: Rl + sred ready

    // ---- Combine (per-wave redundant; no third barrier) ----
    float cv = 0.f;
    if (lane < 24) {
        int c = lane;
        float Sc = S[c];
        float raw = 0.f;
        #pragma unroll
        for (int n = 0; n < 4; ++n) {
            float ss = sred[2 * n][0] + sred[2 * n + 1][0];
            float qq = sred[2 * n][1] + sred[2 * n + 1][1];
            float m   = ss * (1.f / D);
            float var = qq * (1.f / D) - m * m;
            float r   = rsqrtf(var + EPSV);
            raw += r * (Rl[c][n] - m * Sc);
        }
        raw *= 0.25f;
        float t = tanhf(raw);
        if (c < 4) {
            cv = s_beta[c] * t + Bm[c];
        } else if (c < 8) {
            int n = c - 4;
            cv = s_alpha[n * 4] * t + Am[n];
        } else {
            int ij = c - 8;
            cv = s_alpha[ij] * t + Ar[ij];
        }
    }
    // broadcast the 24 coefficients through SGPRs (SALU, not LDS)
    float Bd[4], Amd[4], Ard[4][4];
    #pragma unroll
    for (int n = 0; n < 4; ++n) {
        Bd[n]  = rdlane(cv, n);
        Amd[n] = rdlane(cv, 4 + n);
    }
    #pragma unroll
    for (int i = 0; i < 4; ++i)
        #pragma unroll
        for (int j = 0; j < 4; ++j) Ard[i][j] = rdlane(cv, 8 + i * 4 + j);

    // ---- Phase 3: outputs; thread tid owns float4 d4 = tid ----
    float4 h[4];
    #pragma unroll
    for (int n = 0; n < 4; ++n) {
        uint2 r = ((const uint2*)hq[n])[tid];
        h2 a = ash2(r.x), b = ash2(r.y);
        h[n].x = (float)a[0]; h[n].y = (float)a[1];
        h[n].z = (float)b[0]; h[n].w = (float)b[1];
    }
    float4 mx = {0.f, 0.f, 0.f, 0.f};
    #pragma unroll
    for (int n = 0; n < 4; ++n) {
        mx.x += Amd[n] * h[n].x; mx.y += Amd[n] * h[n].y;
        mx.z += Amd[n] * h[n].z; mx.w += Amd[n] * h[n].w;
    }
    #pragma unroll
    for (int i = 0; i < 4; ++i) {
        float4 o;
        o.x = Bd[i] * lv.x + mx.x;
        o.y = Bd[i] * lv.y + mx.y;
        o.z = Bd[i] * lv.z + mx.z;
        o.w = Bd[i] * lv.w + mx.w;
        #pragma unroll
        for (int j = 0; j < 4; ++j) {
            o.x += Ard[i][j] * h[j].x;
            o.y += Ard[i][j] * h[j].y;
            o.z += Ard[i][j] * h[j].z;
            o.w += Ard[i][j] * h[j].w;
        }
        out4[i * 512 + tid] = o;
    }
}

extern "C" void kernel_launch(void* const* d_in, const int* in_sizes, int n_in,
                              void* d_out, int out_size, void* d_ws, size_t ws_size,
                              hipStream_t stream) {
    const float* lo      = (const float*)d_in[0];
    const float* hs      = (const float*)d_in[1];
    const float* Bm      = (const float*)d_in[2];
    const float* Am      = (const float*)d_in[3];
    const float* Ar      = (const float*)d_in[4];
    const float* s_alpha = (const float*)d_in[5];
    const float* s_beta  = (const float*)d_in[6];
    const float* Wb      = (const float*)d_in[7];
    const float* Wm      = (const float*)d_in[8];
    const float* Wr      = (const float*)d_in[9];
    float* out = (float*)d_out;

    unsigned int* Wq = (unsigned int*)d_ws;                    // 98304 B
    float* S         = (float*)((char*)d_ws + 24 * 1024 * 4);  // 96 B

    wt_kernel<<<24, 256, 0, stream>>>(Wb, Wm, Wr, Wq, S);

    const int tokens = in_sizes[0] / D;            // 8192
    hc_kernel<<<tokens, BLK, 0, stream>>>(lo, hs, Bm, Am, Ar, s_alpha, s_beta,
                                          Wq, S, out);
}